// Round 3
// baseline (732.827 us; speedup 1.0000x reference)
//
#include <hip/hip_runtime.h>

#define Nn 100000
#define Ee 600000
#define Fin 128
#define Hd  256

typedef __attribute__((ext_vector_type(8))) short short8;
typedef __attribute__((ext_vector_type(4))) float floatx4;

__device__ __forceinline__ float bf2f(unsigned short h) {
    return __uint_as_float(((unsigned int)h) << 16);
}
__device__ __forceinline__ unsigned short f2bf(float f) {
    unsigned int u = __float_as_uint(f);
    u += 0x7FFFu + ((u >> 16) & 1u);   // round-to-nearest-even
    return (unsigned short)(u >> 16);
}
// read element i of a float array whose true dtype is f32 (f32flag=1) or bf16 (0)
__device__ __forceinline__ float loadf(const void* p, int i, int f32) {
    return f32 ? ((const float*)p)[i] : bf2f(((const unsigned short*)p)[i]);
}

// ---- runtime probes: flag[0] = edge_index is int64, flag[1] = floats are f32 ----
__global__ void k_detect(const unsigned int* __restrict__ ei,
                         const unsigned short* __restrict__ xu,
                         int* __restrict__ flag) {
    if (blockIdx.x == 0 && threadIdx.x == 0) {
        int is64 = 1;
        for (int i = 1; i < 64; i += 2)
            if (ei[i] != 0u) { is64 = 0; break; }
        flag[0] = is64;
        // f32 data read as bf16: even ushorts are mantissa halves -> huge/NaN exponents appear.
        // true bf16 N(0,1) data never has exponent >= 0xC0 (|v| >= 2^65).
        int isf32 = 0;
        for (int i = 0; i < 512; i += 2) {
            unsigned e = (xu[i] >> 7) & 0xFFu;
            if (e >= 0xC0u) { isf32 = 1; break; }
        }
        flag[1] = isf32;
    }
}

__device__ __forceinline__ void get_edge(const int* __restrict__ ei, int is64, int e,
                                         int& s, int& d) {
    if (is64) { s = ei[2 * e]; d = ei[2 * (Ee + e)]; }
    else      { s = ei[e];     d = ei[Ee + e]; }
}

__global__ void k_zero(int* __restrict__ p, int n) {
    int i = blockIdx.x * 256 + threadIdx.x;
    if (i < n) p[i] = 0;
}

// ---- x -> xb (bf16 internal) ----
__global__ void k_convert(const void* __restrict__ x, unsigned short* __restrict__ xb,
                          const int* __restrict__ flag) {
    int i = (blockIdx.x * 256 + threadIdx.x) * 4;
    if (i >= Nn * Fin) return;
    if (flag[1]) {
        float4 v = ((const float4*)x)[i >> 2];
        ushort4 u;
        u.x = f2bf(v.x); u.y = f2bf(v.y); u.z = f2bf(v.z); u.w = f2bf(v.w);
        ((ushort4*)xb)[i >> 2] = u;
    } else {
        ((ushort4*)xb)[i >> 2] = ((const ushort4*)x)[i >> 2];
    }
}

// ---- weight pre-transpose: Wt[n][k] bf16, concat [Wl;Wr] along k ----
__global__ void k_prep(const void* __restrict__ Wl1, const void* __restrict__ Wr1,
                       const void* __restrict__ Wl2, const void* __restrict__ Wr2,
                       unsigned short* __restrict__ Wt1, unsigned short* __restrict__ Wt2,
                       const int* __restrict__ flag) {
    int f32 = flag[1];
    int tid = blockIdx.x * 256 + threadIdx.x;
    if (tid < 256 * 256) {                 // Wt1: 256 n x 256 k
        int n = tid >> 8, k = tid & 255;
        float v = (k < 128) ? loadf(Wl1, k * 256 + n, f32) : loadf(Wr1, (k - 128) * 256 + n, f32);
        Wt1[n * 256 + k] = f2bf(v);
    }
    int t2 = tid - 256 * 256;
    if (t2 >= 0 && t2 < 256 * 512) {       // Wt2: 256 n x 512 k
        int n = t2 >> 9, k = t2 & 511;
        float v = (k < 256) ? loadf(Wl2, k * 256 + n, f32) : loadf(Wr2, (k - 256) * 256 + n, f32);
        Wt2[n * 512 + k] = f2bf(v);
    }
}

// ---- CSR build ----
__global__ void k_count(const int* __restrict__ ei, const int* __restrict__ flag,
                        int* __restrict__ cnt) {
    int e = blockIdx.x * 256 + threadIdx.x;
    if (e >= Ee) return;
    int is64 = flag[0], s, d;
    get_edge(ei, is64, e, s, d);
    atomicAdd(&cnt[d], 1);
}

__global__ void k_scan(const int* __restrict__ cnt, int* __restrict__ rowptr) {
    __shared__ int part[1024];
    const int T = 1024;
    int t = threadIdx.x;
    const int CH = (Nn + T - 1) / T;
    int lo = t * CH, hi = min(lo + CH, Nn);
    if (lo > Nn) lo = Nn;
    int s = 0;
    for (int i = lo; i < hi; i++) s += cnt[i];
    part[t] = s;
    __syncthreads();
    for (int off = 1; off < T; off <<= 1) {
        int add = (t >= off) ? part[t - off] : 0;
        __syncthreads();
        part[t] += add;
        __syncthreads();
    }
    int pre = (t == 0) ? 0 : part[t - 1];
    for (int i = lo; i < hi; i++) { rowptr[i] = pre; pre += cnt[i]; }
    if (t == T - 1) rowptr[Nn] = part[T - 1];
}

__global__ void k_fill(const int* __restrict__ ei, const int* __restrict__ flag,
                       const int* __restrict__ rowptr, int* __restrict__ cur,
                       int* __restrict__ srcl) {
    int e = blockIdx.x * 256 + threadIdx.x;
    if (e >= Ee) return;
    int is64 = flag[0], s, d;
    get_edge(ei, is64, e, s, d);
    int pos = atomicAdd(&cur[d], 1);
    srcl[rowptr[d] + pos] = s;
}

// ---- gather-based mean aggregation: one wave per node (bf16 in/out, f32 accum) ----
template <int F, int SIN, int SOUT>
__device__ __forceinline__ void agg_body(const unsigned short* __restrict__ X,
                                         unsigned short* __restrict__ O,
                                         const int* __restrict__ rowptr,
                                         const int* __restrict__ srcl) {
    int gw = (blockIdx.x * blockDim.x + threadIdx.x) >> 6;
    int lane = threadIdx.x & 63;
    if (gw >= Nn) return;
    int b = rowptr[gw], e = rowptr[gw + 1];
    constexpr int C = F / 64;
    float acc[C] = {};
    for (int i = b; i < e; i++) {
        int s = srcl[i];
        const unsigned short* row = X + (size_t)s * SIN + lane * C;
        if constexpr (C == 2) {
            ushort2 u = *reinterpret_cast<const ushort2*>(row);
            acc[0] += bf2f(u.x); acc[1] += bf2f(u.y);
        } else {
            ushort4 u = *reinterpret_cast<const ushort4*>(row);
            acc[0] += bf2f(u.x); acc[1] += bf2f(u.y);
            acc[2] += bf2f(u.z); acc[3] += bf2f(u.w);
        }
    }
    float inv = 1.f / (float)max(e - b, 1);
    unsigned short* op = O + (size_t)gw * SOUT + lane * C;
    if constexpr (C == 2) {
        ushort2 u; u.x = f2bf(acc[0] * inv); u.y = f2bf(acc[1] * inv);
        *reinterpret_cast<ushort2*>(op) = u;
    } else {
        ushort4 u;
        u.x = f2bf(acc[0] * inv); u.y = f2bf(acc[1] * inv);
        u.z = f2bf(acc[2] * inv); u.w = f2bf(acc[3] * inv);
        *reinterpret_cast<ushort4*>(op) = u;
    }
}

__global__ void k_agg1(const unsigned short* __restrict__ xb, unsigned short* __restrict__ agg1,
                       const int* __restrict__ rowptr, const int* __restrict__ srcl) {
    agg_body<Fin, Fin, Fin>(xb, agg1, rowptr, srcl);
}

// layer-2 agg: reads h = Acat[:,256:512), writes agg2 = Acat[:,0:256) (disjoint byte halves)
__global__ void k_agg2(const int* __restrict__ rowptr, const int* __restrict__ srcl,
                       const int* __restrict__ flag, unsigned short* __restrict__ acat_ws,
                       void* __restrict__ out) {
    unsigned short* Acat = flag[1] ? (unsigned short*)out : acat_ws;
    agg_body<Hd, 512, 512>(Acat + 256, Acat, rowptr, srcl);
}

// ---- MFMA GEMM core: direct global->fragment loads ----
// a_frag: A[m=lane&15][k=quad*8+j]; b_frag: Wt[n=lane&15][k=quad*8+j];
// C/D: col=lane&15, row=quad*4+reg (verified m89/m91 mapping)
template <int KT, int K1, int S1, int S2>
__device__ __forceinline__ void gemm_core(const unsigned short* __restrict__ A1,
                                          const unsigned short* __restrict__ A2,
                                          const unsigned short* __restrict__ Wt,
                                          floatx4 (&acc)[4][4],
                                          int m_base, int n_base, int quad, int l16) {
    for (int kb = 0; kb < KT; kb += 32) {
        int ko = kb + quad * 8;
        short8 a[4], b[4];
#pragma unroll
        for (int mt = 0; mt < 4; mt++) {
            int m = m_base + mt * 16 + l16;
            if (m >= Nn) m = Nn - 1;  // clamp; stays within the owning block's rows
            const unsigned short* p =
                (ko < K1) ? (A1 + (size_t)m * S1 + ko) : (A2 + (size_t)m * S2 + (ko - K1));
            a[mt] = *reinterpret_cast<const short8*>(p);
        }
#pragma unroll
        for (int nt = 0; nt < 4; nt++) {
            int n = n_base + nt * 16 + l16;
            b[nt] = *reinterpret_cast<const short8*>(Wt + (size_t)n * KT + ko);
        }
#pragma unroll
        for (int mt = 0; mt < 4; mt++)
#pragma unroll
            for (int nt = 0; nt < 4; nt++)
                acc[mt][nt] = __builtin_amdgcn_mfma_f32_16x16x32_bf16(a[mt], b[nt], acc[mt][nt], 0, 0, 0);
    }
}

// layer 1: C = relu([agg1|xb] @ Wt1 + b1) -> h = Acat[:,256:512) (bf16)
__global__ __launch_bounds__(512) void k_gemm1(const unsigned short* __restrict__ agg1,
                                               const unsigned short* __restrict__ xb,
                                               const unsigned short* __restrict__ Wt1,
                                               const void* __restrict__ bias,
                                               const int* __restrict__ flag,
                                               unsigned short* __restrict__ acat_ws,
                                               void* __restrict__ out) {
    int f32 = flag[1];
    unsigned short* Acat = f32 ? (unsigned short*)out : acat_ws;
    int wid = threadIdx.x >> 6, lane = threadIdx.x & 63;
    int wm = wid & 1, wn = wid >> 1;
    int quad = lane >> 4, l16 = lane & 15;
    int m_base = blockIdx.x * 128 + wm * 64;
    int n_base = wn * 64;
    floatx4 acc[4][4] = {};
    gemm_core<256, 128, 128, 128>(agg1, xb, Wt1, acc, m_base, n_base, quad, l16);
#pragma unroll
    for (int nt = 0; nt < 4; nt++) {
        int n = n_base + nt * 16 + l16;
        float bv = loadf(bias, n, f32);
#pragma unroll
        for (int mt = 0; mt < 4; mt++) {
#pragma unroll
            for (int r = 0; r < 4; r++) {
                int m = m_base + mt * 16 + quad * 4 + r;
                if (m < Nn) {
                    float v = acc[mt][nt][r] + bv;
                    v = v > 0.f ? v : 0.f;
                    Acat[(size_t)m * 512 + 256 + n] = f2bf(v);
                }
            }
        }
    }
}

// layer 2: C = [agg2|h] @ Wt2 + b2 -> out (f32 or bf16).
// f32 case: in-place over Acat (1024B A-row == 1024B C-row, block-exclusive rows,
// __syncthreads between all A reads and stores).
__global__ __launch_bounds__(512) void k_gemm2(const unsigned short* __restrict__ Wt2,
                                               const void* __restrict__ bias,
                                               const int* __restrict__ flag,
                                               unsigned short* __restrict__ acat_ws,
                                               void* __restrict__ out) {
    int f32 = flag[1];
    unsigned short* Acat = f32 ? (unsigned short*)out : acat_ws;
    int wid = threadIdx.x >> 6, lane = threadIdx.x & 63;
    int wm = wid & 1, wn = wid >> 1;
    int quad = lane >> 4, l16 = lane & 15;
    int m_base = blockIdx.x * 128 + wm * 64;
    int n_base = wn * 64;
    floatx4 acc[4][4] = {};
    gemm_core<512, 256, 512, 512>(Acat, Acat + 256, Wt2, acc, m_base, n_base, quad, l16);
    __syncthreads();   // all A reads in this block complete before any in-place store
#pragma unroll
    for (int nt = 0; nt < 4; nt++) {
        int n = n_base + nt * 16 + l16;
        float bv = loadf(bias, n, f32);
#pragma unroll
        for (int mt = 0; mt < 4; mt++) {
#pragma unroll
            for (int r = 0; r < 4; r++) {
                int m = m_base + mt * 16 + quad * 4 + r;
                if (m < Nn) {
                    float v = acc[mt][nt][r] + bv;
                    if (f32) ((float*)out)[(size_t)m * Hd + n] = v;
                    else     ((unsigned short*)out)[(size_t)m * Hd + n] = f2bf(v);
                }
            }
        }
    }
}

extern "C" void kernel_launch(void* const* d_in, const int* in_sizes, int n_in,
                              void* d_out, int out_size, void* d_ws, size_t ws_size,
                              hipStream_t stream) {
    const void* x   = d_in[0];
    const int*  ei  = (const int*)d_in[1];
    const void* Wl1 = d_in[2];
    const void* Wr1 = d_in[3];
    const void* b1  = d_in[4];
    const void* Wl2 = d_in[5];
    const void* Wr2 = d_in[6];
    const void* b2  = d_in[7];

    char* ws = (char*)d_ws;
    size_t off_cnt    = 0;                                    // N ints
    size_t off_cur    = off_cnt + (size_t)Nn * 4;             // N ints
    size_t off_rowptr = off_cur + (size_t)Nn * 4;             // N+4 ints
    size_t off_srcl   = off_rowptr + (size_t)(Nn + 4) * 4;    // E ints
    size_t off_flag   = off_srcl + (size_t)Ee * 4;            // 2 ints
    size_t off_wt1    = ((off_flag + 8 + 255) / 256) * 256;   // 256*256 bf16
    size_t off_wt2    = off_wt1 + 256 * 256 * 2;              // 256*512 bf16
    size_t off_xb     = off_wt2 + 256 * 512 * 2;              // N*128 bf16
    size_t off_agg1   = off_xb + (size_t)Nn * Fin * 2;        // N*128 bf16
    size_t off_acat   = off_agg1 + (size_t)Nn * Fin * 2;      // N*512 bf16 (touched only if bf16 harness)

    int*            cnt     = (int*)(ws + off_cnt);
    int*            cur     = (int*)(ws + off_cur);
    int*            rowptr  = (int*)(ws + off_rowptr);
    int*            srcl    = (int*)(ws + off_srcl);
    int*            flag    = (int*)(ws + off_flag);
    unsigned short* Wt1     = (unsigned short*)(ws + off_wt1);
    unsigned short* Wt2     = (unsigned short*)(ws + off_wt2);
    unsigned short* xb      = (unsigned short*)(ws + off_xb);
    unsigned short* agg1    = (unsigned short*)(ws + off_agg1);
    unsigned short* acat_ws = (unsigned short*)(ws + off_acat);

    k_detect<<<1, 64, 0, stream>>>((const unsigned int*)ei, (const unsigned short*)x, flag);
    k_zero<<<(2 * Nn + 255) / 256, 256, 0, stream>>>(cnt, 2 * Nn);
    k_convert<<<(Nn * Fin / 4 + 255) / 256, 256, 0, stream>>>(x, xb, flag);
    k_prep<<<768, 256, 0, stream>>>(Wl1, Wr1, Wl2, Wr2, Wt1, Wt2, flag);

    int eb = (Ee + 255) / 256;
    k_count<<<eb, 256, 0, stream>>>(ei, flag, cnt);
    k_scan<<<1, 1024, 0, stream>>>(cnt, rowptr);
    k_fill<<<eb, 256, 0, stream>>>(ei, flag, rowptr, cur, srcl);

    int ab = (Nn * 64 + 255) / 256;   // one wave per node
    int gx = (Nn + 127) / 128;

    k_agg1<<<ab, 256, 0, stream>>>(xb, agg1, rowptr, srcl);
    k_gemm1<<<gx, 512, 0, stream>>>(agg1, xb, Wt1, b1, flag, acat_ws, d_out);
    k_agg2<<<ab, 256, 0, stream>>>(rowptr, srcl, flag, acat_ws, d_out);
    k_gemm2<<<gx, 512, 0, stream>>>(Wt2, b2, flag, acat_ws, d_out);
}

// Round 4
// 670.177 us; speedup vs baseline: 1.0935x; 1.0935x over previous
//
#include <hip/hip_runtime.h>

#define Nn 100000
#define Ee 600000
#define Fin 128
#define Hd  256

typedef __attribute__((ext_vector_type(8))) short short8;
typedef __attribute__((ext_vector_type(4))) float floatx4;

__device__ __forceinline__ float bf2f(unsigned short h) {
    return __uint_as_float(((unsigned int)h) << 16);
}
__device__ __forceinline__ unsigned short f2bf(float f) {
    unsigned int u = __float_as_uint(f);
    u += 0x7FFFu + ((u >> 16) & 1u);   // round-to-nearest-even
    return (unsigned short)(u >> 16);
}
__device__ __forceinline__ float loadf(const void* p, int i, int f32) {
    return f32 ? ((const float*)p)[i] : bf2f(((const unsigned short*)p)[i]);
}
// async global->LDS, 16B per lane; lds dest must be wave-uniform base (+lane*16 implicit)
__device__ __forceinline__ void gload_lds16(const void* g, void* lds) {
    __builtin_amdgcn_global_load_lds((const __attribute__((address_space(1))) void*)g,
                                     (__attribute__((address_space(3))) void*)lds,
                                     16, 0, 0);
}

// ---- runtime probes: flag[0] = edge_index is int64, flag[1] = floats are f32 ----
__global__ void k_detect(const unsigned int* __restrict__ ei,
                         const unsigned short* __restrict__ xu,
                         int* __restrict__ flag) {
    if (blockIdx.x == 0 && threadIdx.x == 0) {
        int is64 = 1;
        for (int i = 1; i < 64; i += 2)
            if (ei[i] != 0u) { is64 = 0; break; }
        flag[0] = is64;
        int isf32 = 0;
        for (int i = 0; i < 512; i += 2) {
            unsigned e = (xu[i] >> 7) & 0xFFu;
            if (e >= 0xC0u) { isf32 = 1; break; }
        }
        flag[1] = isf32;
    }
}

__device__ __forceinline__ void get_edge(const int* __restrict__ ei, int is64, int e,
                                         int& s, int& d) {
    if (is64) { s = ei[2 * e]; d = ei[2 * (Ee + e)]; }
    else      { s = ei[e];     d = ei[Ee + e]; }
}

__global__ void k_zero(int* __restrict__ p, int n) {
    int i = blockIdx.x * 256 + threadIdx.x;
    if (i < n) p[i] = 0;
}

// ---- x -> xb (bf16 internal) ----
__global__ void k_convert(const void* __restrict__ x, unsigned short* __restrict__ xb,
                          const int* __restrict__ flag) {
    int i = (blockIdx.x * 256 + threadIdx.x) * 4;
    if (i >= Nn * Fin) return;
    if (flag[1]) {
        float4 v = ((const float4*)x)[i >> 2];
        ushort4 u;
        u.x = f2bf(v.x); u.y = f2bf(v.y); u.z = f2bf(v.z); u.w = f2bf(v.w);
        ((ushort4*)xb)[i >> 2] = u;
    } else {
        ((ushort4*)xb)[i >> 2] = ((const ushort4*)x)[i >> 2];
    }
}

// ---- weight pre-transpose: Wt[n][k] bf16, concat [Wl;Wr] along k ----
__global__ void k_prep(const void* __restrict__ Wl1, const void* __restrict__ Wr1,
                       const void* __restrict__ Wl2, const void* __restrict__ Wr2,
                       unsigned short* __restrict__ Wt1, unsigned short* __restrict__ Wt2,
                       const int* __restrict__ flag) {
    int f32 = flag[1];
    int tid = blockIdx.x * 256 + threadIdx.x;
    if (tid < 256 * 256) {
        int n = tid >> 8, k = tid & 255;
        float v = (k < 128) ? loadf(Wl1, k * 256 + n, f32) : loadf(Wr1, (k - 128) * 256 + n, f32);
        Wt1[n * 256 + k] = f2bf(v);
    }
    int t2 = tid - 256 * 256;
    if (t2 >= 0 && t2 < 256 * 512) {
        int n = t2 >> 9, k = t2 & 511;
        float v = (k < 256) ? loadf(Wl2, k * 256 + n, f32) : loadf(Wr2, (k - 256) * 256 + n, f32);
        Wt2[n * 512 + k] = f2bf(v);
    }
}

// ---- CSR build ----
__global__ void k_count(const int* __restrict__ ei, const int* __restrict__ flag,
                        int* __restrict__ cnt) {
    int e = blockIdx.x * 256 + threadIdx.x;
    if (e >= Ee) return;
    int is64 = flag[0], s, d;
    get_edge(ei, is64, e, s, d);
    atomicAdd(&cnt[d], 1);
}

__global__ void k_scan(const int* __restrict__ cnt, int* __restrict__ rowptr) {
    __shared__ int part[1024];
    const int T = 1024;
    int t = threadIdx.x;
    const int CH = (Nn + T - 1) / T;
    int lo = t * CH, hi = min(lo + CH, Nn);
    if (lo > Nn) lo = Nn;
    int s = 0;
    for (int i = lo; i < hi; i++) s += cnt[i];
    part[t] = s;
    __syncthreads();
    for (int off = 1; off < T; off <<= 1) {
        int add = (t >= off) ? part[t - off] : 0;
        __syncthreads();
        part[t] += add;
        __syncthreads();
    }
    int pre = (t == 0) ? 0 : part[t - 1];
    for (int i = lo; i < hi; i++) { rowptr[i] = pre; pre += cnt[i]; }
    if (t == T - 1) rowptr[Nn] = part[T - 1];
}

__global__ void k_fill(const int* __restrict__ ei, const int* __restrict__ flag,
                       const int* __restrict__ rowptr, int* __restrict__ cur,
                       int* __restrict__ srcl) {
    int e = blockIdx.x * 256 + threadIdx.x;
    if (e >= Ee) return;
    int is64 = flag[0], s, d;
    get_edge(ei, is64, e, s, d);
    int pos = atomicAdd(&cur[d], 1);
    srcl[rowptr[d] + pos] = s;
}

// ---- gather-based mean aggregation: one wave per node (bf16 in/out, f32 accum) ----
template <int F, int SIN, int SOUT>
__device__ __forceinline__ void agg_body(const unsigned short* __restrict__ X,
                                         unsigned short* __restrict__ O,
                                         const int* __restrict__ rowptr,
                                         const int* __restrict__ srcl) {
    int gw = (blockIdx.x * blockDim.x + threadIdx.x) >> 6;
    int lane = threadIdx.x & 63;
    if (gw >= Nn) return;
    int b = rowptr[gw], e = rowptr[gw + 1];
    constexpr int C = F / 64;
    float acc[C] = {};
    for (int i = b; i < e; i++) {
        int s = srcl[i];
        const unsigned short* row = X + (size_t)s * SIN + lane * C;
        if constexpr (C == 2) {
            ushort2 u = *reinterpret_cast<const ushort2*>(row);
            acc[0] += bf2f(u.x); acc[1] += bf2f(u.y);
        } else {
            ushort4 u = *reinterpret_cast<const ushort4*>(row);
            acc[0] += bf2f(u.x); acc[1] += bf2f(u.y);
            acc[2] += bf2f(u.z); acc[3] += bf2f(u.w);
        }
    }
    float inv = 1.f / (float)max(e - b, 1);
    unsigned short* op = O + (size_t)gw * SOUT + lane * C;
    if constexpr (C == 2) {
        ushort2 u; u.x = f2bf(acc[0] * inv); u.y = f2bf(acc[1] * inv);
        *reinterpret_cast<ushort2*>(op) = u;
    } else {
        ushort4 u;
        u.x = f2bf(acc[0] * inv); u.y = f2bf(acc[1] * inv);
        u.z = f2bf(acc[2] * inv); u.w = f2bf(acc[3] * inv);
        *reinterpret_cast<ushort4*>(op) = u;
    }
}

__global__ void k_agg1(const unsigned short* __restrict__ xb, unsigned short* __restrict__ agg1,
                       const int* __restrict__ rowptr, const int* __restrict__ srcl) {
    agg_body<Fin, Fin, Fin>(xb, agg1, rowptr, srcl);
}

__global__ void k_agg2(const int* __restrict__ rowptr, const int* __restrict__ srcl,
                       const int* __restrict__ flag, unsigned short* __restrict__ acat_ws,
                       void* __restrict__ out) {
    unsigned short* Acat = flag[1] ? (unsigned short*)out : acat_ws;
    agg_body<Hd, 512, 512>(Acat + 256, Acat, rowptr, srcl);
}

// ---- MFMA GEMM core with async LDS A-staging ----
// A-tile 128m x 64k bf16 = 16 KB. Staged via global_load_lds(16B):
// thread t (of 512), issue i in {0,1}: tile row r = i*64 + t/8, chunk c = t&7;
// global k-chunk fetched = c ^ (r&7)  (XOR swizzle -> 2-way-bank-free ds_reads
// while keeping the mandatory "base + lane*16" LDS identity layout).
// LDS(r, c) holds global chunk c^(r&7); reader of chunk q reads c = q^(r&7).
// a_frag: A[m=lane&15][k=quad*8+j]; b_frag direct from global Wt[n][k] (L2-resident).
// C/D: col=lane&15, row=quad*4+reg.
template <int KT, int K1, int S1, int S2>
__device__ __forceinline__ void gemm_core_lds(const unsigned short* __restrict__ A1,
                                              const unsigned short* __restrict__ A2,
                                              const unsigned short* __restrict__ Wt,
                                              floatx4 (&acc)[4][4],
                                              unsigned short* sA, int m_base) {
    const int tid = threadIdx.x;
    const int lane = tid & 63, wid = tid >> 6;
    const int wm = wid & 1, wn = wid >> 1;
    const int quad = lane >> 4, l16 = lane & 15;
    const int n_base = wn * 64;
    const int rs = tid >> 3;        // staging row (issue 0), 0..63
    const int cs = tid & 7;         // staging chunk

    for (int kb = 0; kb < KT; kb += 64) {
        __syncthreads();            // previous tile fully consumed
#pragma unroll
        for (int i = 0; i < 2; i++) {
            int r = i * 64 + rs;
            int gk = kb + ((cs ^ (r & 7)) << 3);
            int m = m_base + r; if (m >= Nn) m = Nn - 1;   // clamp, stays in-block
            const unsigned short* gp = (gk < K1)
                ? A1 + (size_t)m * S1 + gk
                : A2 + (size_t)m * S2 + (gk - K1);
            gload_lds16(gp, sA + i * 4096 + wid * 512);    // wave-uniform lds base
        }
        __syncthreads();            // staging complete (compiler drains vmcnt)
#pragma unroll
        for (int ks = 0; ks < 64; ks += 32) {
            short8 a[4], b[4];
#pragma unroll
            for (int mt = 0; mt < 4; mt++) {
                int r = wm * 64 + mt * 16 + l16;
                int q = (ks >> 3) + quad;
                a[mt] = *reinterpret_cast<const short8*>(
                    sA + r * 64 + ((q ^ (l16 & 7)) << 3));
            }
#pragma unroll
            for (int nt = 0; nt < 4; nt++) {
                int n = n_base + nt * 16 + l16;
                b[nt] = *reinterpret_cast<const short8*>(
                    Wt + (size_t)n * KT + kb + ks + quad * 8);
            }
#pragma unroll
            for (int mt = 0; mt < 4; mt++)
#pragma unroll
                for (int nt = 0; nt < 4; nt++)
                    acc[mt][nt] = __builtin_amdgcn_mfma_f32_16x16x32_bf16(a[mt], b[nt], acc[mt][nt], 0, 0, 0);
        }
    }
}

// layer 1: h = relu([agg1|xb] @ Wt1 + b1) -> Acat[:,256:512) (bf16)
__global__ __launch_bounds__(512) void k_gemm1(const unsigned short* __restrict__ agg1,
                                               const unsigned short* __restrict__ xb,
                                               const unsigned short* __restrict__ Wt1,
                                               const void* __restrict__ bias,
                                               const int* __restrict__ flag,
                                               unsigned short* __restrict__ acat_ws,
                                               void* __restrict__ out) {
    __shared__ unsigned short sA[8192];
    int f32 = flag[1];
    unsigned short* Acat = f32 ? (unsigned short*)out : acat_ws;
    int wid = threadIdx.x >> 6, lane = threadIdx.x & 63;
    int wm = wid & 1, wn = wid >> 1;
    int quad = lane >> 4, l16 = lane & 15;
    int m_base = blockIdx.x * 128;
    floatx4 acc[4][4] = {};
    gemm_core_lds<256, 128, 128, 128>(agg1, xb, Wt1, acc, sA, m_base);
#pragma unroll
    for (int nt = 0; nt < 4; nt++) {
        int n = wn * 64 + nt * 16 + l16;
        float bv = loadf(bias, n, f32);
#pragma unroll
        for (int mt = 0; mt < 4; mt++) {
#pragma unroll
            for (int r = 0; r < 4; r++) {
                int m = m_base + wm * 64 + mt * 16 + quad * 4 + r;
                if (m < Nn) {
                    float v = acc[mt][nt][r] + bv;
                    v = v > 0.f ? v : 0.f;
                    Acat[(size_t)m * 512 + 256 + n] = f2bf(v);
                }
            }
        }
    }
}

// layer 2: out = [agg2|h] @ Wt2 + b2. f32 path writes in place over Acat
// (block-exclusive rows; all global A reads finished before last in-loop barrier).
__global__ __launch_bounds__(512) void k_gemm2(const unsigned short* __restrict__ Wt2,
                                               const void* __restrict__ bias,
                                               const int* __restrict__ flag,
                                               unsigned short* __restrict__ acat_ws,
                                               void* __restrict__ out) {
    __shared__ unsigned short sA[8192];
    int f32 = flag[1];
    unsigned short* Acat = f32 ? (unsigned short*)out : acat_ws;
    int wid = threadIdx.x >> 6, lane = threadIdx.x & 63;
    int wm = wid & 1, wn = wid >> 1;
    int quad = lane >> 4, l16 = lane & 15;
    int m_base = blockIdx.x * 128;
    floatx4 acc[4][4] = {};
    gemm_core_lds<512, 256, 512, 512>(Acat, Acat + 256, Wt2, acc, sA, m_base);
    __syncthreads();   // belt-and-suspenders before in-place stores
#pragma unroll
    for (int nt = 0; nt < 4; nt++) {
        int n = wn * 64 + nt * 16 + l16;
        float bv = loadf(bias, n, f32);
#pragma unroll
        for (int mt = 0; mt < 4; mt++) {
#pragma unroll
            for (int r = 0; r < 4; r++) {
                int m = m_base + wm * 64 + mt * 16 + quad * 4 + r;
                if (m < Nn) {
                    float v = acc[mt][nt][r] + bv;
                    if (f32) ((float*)out)[(size_t)m * Hd + n] = v;
                    else     ((unsigned short*)out)[(size_t)m * Hd + n] = f2bf(v);
                }
            }
        }
    }
}

extern "C" void kernel_launch(void* const* d_in, const int* in_sizes, int n_in,
                              void* d_out, int out_size, void* d_ws, size_t ws_size,
                              hipStream_t stream) {
    const void* x   = d_in[0];
    const int*  ei  = (const int*)d_in[1];
    const void* Wl1 = d_in[2];
    const void* Wr1 = d_in[3];
    const void* b1  = d_in[4];
    const void* Wl2 = d_in[5];
    const void* Wr2 = d_in[6];
    const void* b2  = d_in[7];

    char* ws = (char*)d_ws;
    size_t off_cnt    = 0;
    size_t off_cur    = off_cnt + (size_t)Nn * 4;
    size_t off_rowptr = off_cur + (size_t)Nn * 4;
    size_t off_srcl   = off_rowptr + (size_t)(Nn + 4) * 4;
    size_t off_flag   = off_srcl + (size_t)Ee * 4;
    size_t off_wt1    = ((off_flag + 8 + 255) / 256) * 256;
    size_t off_wt2    = off_wt1 + 256 * 256 * 2;
    size_t off_xb     = off_wt2 + 256 * 512 * 2;
    size_t off_agg1   = off_xb + (size_t)Nn * Fin * 2;
    size_t off_acat   = off_agg1 + (size_t)Nn * Fin * 2;  // only touched in bf16 mode

    int*            cnt     = (int*)(ws + off_cnt);
    int*            cur     = (int*)(ws + off_cur);
    int*            rowptr  = (int*)(ws + off_rowptr);
    int*            srcl    = (int*)(ws + off_srcl);
    int*            flag    = (int*)(ws + off_flag);
    unsigned short* Wt1     = (unsigned short*)(ws + off_wt1);
    unsigned short* Wt2     = (unsigned short*)(ws + off_wt2);
    unsigned short* xb      = (unsigned short*)(ws + off_xb);
    unsigned short* agg1    = (unsigned short*)(ws + off_agg1);
    unsigned short* acat_ws = (unsigned short*)(ws + off_acat);

    k_detect<<<1, 64, 0, stream>>>((const unsigned int*)ei, (const unsigned short*)x, flag);
    k_zero<<<(2 * Nn + 255) / 256, 256, 0, stream>>>(cnt, 2 * Nn);
    k_convert<<<(Nn * Fin / 4 + 255) / 256, 256, 0, stream>>>(x, xb, flag);
    k_prep<<<768, 256, 0, stream>>>(Wl1, Wr1, Wl2, Wr2, Wt1, Wt2, flag);

    int eb = (Ee + 255) / 256;
    k_count<<<eb, 256, 0, stream>>>(ei, flag, cnt);
    k_scan<<<1, 1024, 0, stream>>>(cnt, rowptr);
    k_fill<<<eb, 256, 0, stream>>>(ei, flag, rowptr, cur, srcl);

    int ab = (Nn * 64 + 255) / 256;
    int gx = (Nn + 127) / 128;

    k_agg1<<<ab, 256, 0, stream>>>(xb, agg1, rowptr, srcl);
    k_gemm1<<<gx, 512, 0, stream>>>(agg1, xb, Wt1, b1, flag, acat_ws, d_out);
    k_agg2<<<ab, 256, 0, stream>>>(rowptr, srcl, flag, acat_ws, d_out);
    k_gemm2<<<gx, 512, 0, stream>>>(Wt2, b2, flag, acat_ws, d_out);
}

// Round 5
// 516.077 us; speedup vs baseline: 1.4200x; 1.2986x over previous
//
#include <hip/hip_runtime.h>

#define Nn 100000
#define Ee 600000
#define Fin 128
#define Hd  256
#define NB  ((Nn + 1023) / 1024)   // 98 scan blocks

typedef __attribute__((ext_vector_type(8))) short short8;
typedef __attribute__((ext_vector_type(4))) float floatx4;

__device__ __forceinline__ float bf2f(unsigned short h) {
    return __uint_as_float(((unsigned int)h) << 16);
}
__device__ __forceinline__ unsigned short f2bf(float f) {
    unsigned int u = __float_as_uint(f);
    u += 0x7FFFu + ((u >> 16) & 1u);   // round-to-nearest-even
    return (unsigned short)(u >> 16);
}
__device__ __forceinline__ float loadf(const void* p, int i, int f32) {
    return f32 ? ((const float*)p)[i] : bf2f(((const unsigned short*)p)[i]);
}
__device__ __forceinline__ void gload_lds16(const void* g, void* lds) {
    __builtin_amdgcn_global_load_lds((const __attribute__((address_space(1))) void*)g,
                                     (__attribute__((address_space(3))) void*)lds,
                                     16, 0, 0);
}

// ---- runtime probes: flag[0] = edge_index is int64, flag[1] = floats are f32 ----
__global__ void k_detect(const unsigned int* __restrict__ ei,
                         const unsigned short* __restrict__ xu,
                         int* __restrict__ flag) {
    if (blockIdx.x == 0 && threadIdx.x == 0) {
        int is64 = 1;
        for (int i = 1; i < 64; i += 2)
            if (ei[i] != 0u) { is64 = 0; break; }
        flag[0] = is64;
        int isf32 = 0;
        for (int i = 0; i < 512; i += 2) {
            unsigned e = (xu[i] >> 7) & 0xFFu;
            if (e >= 0xC0u) { isf32 = 1; break; }
        }
        flag[1] = isf32;
    }
}

__device__ __forceinline__ void get_edge(const int* __restrict__ ei, int is64, int e,
                                         int& s, int& d) {
    if (is64) { s = ei[2 * e]; d = ei[2 * (Ee + e)]; }
    else      { s = ei[e];     d = ei[Ee + e]; }
}

__global__ void k_zero(int* __restrict__ p, int n) {
    int i = blockIdx.x * 256 + threadIdx.x;
    if (i < n) p[i] = 0;
}

// ---- x -> xb (bf16 internal) ----
__global__ void k_convert(const void* __restrict__ x, unsigned short* __restrict__ xb,
                          const int* __restrict__ flag) {
    int i = (blockIdx.x * 256 + threadIdx.x) * 4;
    if (i >= Nn * Fin) return;
    if (flag[1]) {
        float4 v = ((const float4*)x)[i >> 2];
        ushort4 u;
        u.x = f2bf(v.x); u.y = f2bf(v.y); u.z = f2bf(v.z); u.w = f2bf(v.w);
        ((ushort4*)xb)[i >> 2] = u;
    } else {
        ((ushort4*)xb)[i >> 2] = ((const ushort4*)x)[i >> 2];
    }
}

// ---- weight pre-transpose: Wt[n][k] bf16, concat [Wl;Wr] along k ----
__global__ void k_prep(const void* __restrict__ Wl1, const void* __restrict__ Wr1,
                       const void* __restrict__ Wl2, const void* __restrict__ Wr2,
                       unsigned short* __restrict__ Wt1, unsigned short* __restrict__ Wt2,
                       const int* __restrict__ flag) {
    int f32 = flag[1];
    int tid = blockIdx.x * 256 + threadIdx.x;
    if (tid < 256 * 256) {
        int n = tid >> 8, k = tid & 255;
        float v = (k < 128) ? loadf(Wl1, k * 256 + n, f32) : loadf(Wr1, (k - 128) * 256 + n, f32);
        Wt1[n * 256 + k] = f2bf(v);
    }
    int t2 = tid - 256 * 256;
    if (t2 >= 0 && t2 < 256 * 512) {
        int n = t2 >> 9, k = t2 & 511;
        float v = (k < 256) ? loadf(Wl2, k * 256 + n, f32) : loadf(Wr2, (k - 256) * 256 + n, f32);
        Wt2[n * 512 + k] = f2bf(v);
    }
}

// ---- CSR build ----
__global__ void k_count(const int* __restrict__ ei, const int* __restrict__ flag,
                        int* __restrict__ cnt) {
    int e = blockIdx.x * 256 + threadIdx.x;
    if (e >= Ee) return;
    int is64 = flag[0], s, d;
    get_edge(ei, is64, e, s, d);
    atomicAdd(&cnt[d], 1);
}

// hierarchical scan: k_bsum -> k_bscan -> k_rowptr (all coalesced int4)
__global__ void k_bsum(const int* __restrict__ cnt, int* __restrict__ bsum) {
    __shared__ int red[256];
    int b = blockIdx.x, t = threadIdx.x;
    int i = b * 1024 + t * 4;
    int s = 0;
    if (i + 3 < Nn) {
        int4 v = *reinterpret_cast<const int4*>(cnt + i);
        s = v.x + v.y + v.z + v.w;
    } else {
        for (int j = 0; j < 4; j++) if (i + j < Nn) s += cnt[i + j];
    }
    red[t] = s;
    __syncthreads();
    for (int off = 128; off > 0; off >>= 1) {
        if (t < off) red[t] += red[t + off];
        __syncthreads();
    }
    if (t == 0) bsum[b] = red[0];
}

__global__ void k_bscan(const int* __restrict__ bsum, int* __restrict__ bpre,
                        int* __restrict__ rowptr) {
    __shared__ int sc[128];
    int t = threadIdx.x;
    int v = (t < NB) ? bsum[t] : 0;
    sc[t] = v;
    __syncthreads();
    for (int off = 1; off < 128; off <<= 1) {
        int add = (t >= off) ? sc[t - off] : 0;
        __syncthreads();
        sc[t] += add;
        __syncthreads();
    }
    if (t < NB) bpre[t] = sc[t] - v;          // exclusive prefix
    if (t == 127) rowptr[Nn] = sc[127];       // grand total (== Ee)
}

__global__ void k_rowptr(const int* __restrict__ cnt, const int* __restrict__ bpre,
                         int* __restrict__ rowptr) {
    __shared__ int sc[256];
    int b = blockIdx.x, t = threadIdx.x;
    int i = b * 1024 + t * 4;
    int4 c = make_int4(0, 0, 0, 0);
    if (i + 3 < Nn) {
        c = *reinterpret_cast<const int4*>(cnt + i);
    } else {
        if (i     < Nn) c.x = cnt[i];
        if (i + 1 < Nn) c.y = cnt[i + 1];
        if (i + 2 < Nn) c.z = cnt[i + 2];
        if (i + 3 < Nn) c.w = cnt[i + 3];
    }
    int s = c.x + c.y + c.z + c.w;
    sc[t] = s;
    __syncthreads();
    for (int off = 1; off < 256; off <<= 1) {
        int add = (t >= off) ? sc[t - off] : 0;
        __syncthreads();
        sc[t] += add;
        __syncthreads();
    }
    int p = bpre[b] + sc[t] - s;   // exclusive prefix of element i
    int4 r;
    r.x = p;
    r.y = r.x + c.x;
    r.z = r.y + c.y;
    r.w = r.z + c.z;
    if (i + 3 < Nn) {
        *reinterpret_cast<int4*>(rowptr + i) = r;
    } else {
        if (i     < Nn) rowptr[i]     = r.x;
        if (i + 1 < Nn) rowptr[i + 1] = r.y;
        if (i + 2 < Nn) rowptr[i + 2] = r.z;
        if (i + 3 < Nn) rowptr[i + 3] = r.w;
    }
}

__global__ void k_fill(const int* __restrict__ ei, const int* __restrict__ flag,
                       const int* __restrict__ rowptr, int* __restrict__ cur,
                       int* __restrict__ srcl) {
    int e = blockIdx.x * 256 + threadIdx.x;
    if (e >= Ee) return;
    int is64 = flag[0], s, d;
    get_edge(ei, is64, e, s, d);
    int pos = atomicAdd(&cur[d], 1);
    srcl[rowptr[d] + pos] = s;
}

// ---- gather-based mean aggregation: one wave per node (bf16 in/out, f32 accum) ----
template <int F, int SIN, int SOUT>
__device__ __forceinline__ void agg_body(const unsigned short* __restrict__ X,
                                         unsigned short* __restrict__ O,
                                         const int* __restrict__ rowptr,
                                         const int* __restrict__ srcl) {
    int gw = (blockIdx.x * blockDim.x + threadIdx.x) >> 6;
    int lane = threadIdx.x & 63;
    if (gw >= Nn) return;
    int b = rowptr[gw], e = rowptr[gw + 1];
    constexpr int C = F / 64;
    float acc[C] = {};
    for (int i = b; i < e; i++) {
        int s = srcl[i];
        const unsigned short* row = X + (size_t)s * SIN + lane * C;
        if constexpr (C == 2) {
            ushort2 u = *reinterpret_cast<const ushort2*>(row);
            acc[0] += bf2f(u.x); acc[1] += bf2f(u.y);
        } else {
            ushort4 u = *reinterpret_cast<const ushort4*>(row);
            acc[0] += bf2f(u.x); acc[1] += bf2f(u.y);
            acc[2] += bf2f(u.z); acc[3] += bf2f(u.w);
        }
    }
    float inv = 1.f / (float)max(e - b, 1);
    unsigned short* op = O + (size_t)gw * SOUT + lane * C;
    if constexpr (C == 2) {
        ushort2 u; u.x = f2bf(acc[0] * inv); u.y = f2bf(acc[1] * inv);
        *reinterpret_cast<ushort2*>(op) = u;
    } else {
        ushort4 u;
        u.x = f2bf(acc[0] * inv); u.y = f2bf(acc[1] * inv);
        u.z = f2bf(acc[2] * inv); u.w = f2bf(acc[3] * inv);
        *reinterpret_cast<ushort4*>(op) = u;
    }
}

__global__ void k_agg1(const unsigned short* __restrict__ xb, unsigned short* __restrict__ agg1,
                       const int* __restrict__ rowptr, const int* __restrict__ srcl) {
    agg_body<Fin, Fin, Fin>(xb, agg1, rowptr, srcl);
}

__global__ void k_agg2(const int* __restrict__ rowptr, const int* __restrict__ srcl,
                       const int* __restrict__ flag, unsigned short* __restrict__ acat_ws,
                       void* __restrict__ out) {
    unsigned short* Acat = flag[1] ? (unsigned short*)out : acat_ws;
    agg_body<Hd, 512, 512>(Acat + 256, Acat, rowptr, srcl);
}

// ---- MFMA GEMM core with async LDS A-staging (XOR k-chunk swizzle) ----
template <int KT, int K1, int S1, int S2>
__device__ __forceinline__ void gemm_core_lds(const unsigned short* __restrict__ A1,
                                              const unsigned short* __restrict__ A2,
                                              const unsigned short* __restrict__ Wt,
                                              floatx4 (&acc)[4][4],
                                              unsigned short* sA, int m_base) {
    const int tid = threadIdx.x;
    const int lane = tid & 63, wid = tid >> 6;
    const int wm = wid & 1, wn = wid >> 1;
    const int quad = lane >> 4, l16 = lane & 15;
    const int n_base = wn * 64;
    const int rs = tid >> 3;
    const int cs = tid & 7;

    for (int kb = 0; kb < KT; kb += 64) {
        __syncthreads();
#pragma unroll
        for (int i = 0; i < 2; i++) {
            int r = i * 64 + rs;
            int gk = kb + ((cs ^ (r & 7)) << 3);
            int m = m_base + r; if (m >= Nn) m = Nn - 1;
            const unsigned short* gp = (gk < K1)
                ? A1 + (size_t)m * S1 + gk
                : A2 + (size_t)m * S2 + (gk - K1);
            gload_lds16(gp, sA + i * 4096 + wid * 512);
        }
        __syncthreads();
#pragma unroll
        for (int ks = 0; ks < 64; ks += 32) {
            short8 a[4], b[4];
#pragma unroll
            for (int mt = 0; mt < 4; mt++) {
                int r = wm * 64 + mt * 16 + l16;
                int q = (ks >> 3) + quad;
                a[mt] = *reinterpret_cast<const short8*>(
                    sA + r * 64 + ((q ^ (l16 & 7)) << 3));
            }
#pragma unroll
            for (int nt = 0; nt < 4; nt++) {
                int n = n_base + nt * 16 + l16;
                b[nt] = *reinterpret_cast<const short8*>(
                    Wt + (size_t)n * KT + kb + ks + quad * 8);
            }
#pragma unroll
            for (int mt = 0; mt < 4; mt++)
#pragma unroll
                for (int nt = 0; nt < 4; nt++)
                    acc[mt][nt] = __builtin_amdgcn_mfma_f32_16x16x32_bf16(a[mt], b[nt], acc[mt][nt], 0, 0, 0);
        }
    }
}

// layer 1: h = relu([agg1|xb] @ Wt1 + b1) -> Acat[:,256:512) (bf16)
__global__ __launch_bounds__(512) void k_gemm1(const unsigned short* __restrict__ agg1,
                                               const unsigned short* __restrict__ xb,
                                               const unsigned short* __restrict__ Wt1,
                                               const void* __restrict__ bias,
                                               const int* __restrict__ flag,
                                               unsigned short* __restrict__ acat_ws,
                                               void* __restrict__ out) {
    __shared__ unsigned short sA[8192];
    int f32 = flag[1];
    unsigned short* Acat = f32 ? (unsigned short*)out : acat_ws;
    int wid = threadIdx.x >> 6, lane = threadIdx.x & 63;
    int wm = wid & 1, wn = wid >> 1;
    int quad = lane >> 4, l16 = lane & 15;
    int m_base = blockIdx.x * 128;
    floatx4 acc[4][4] = {};
    gemm_core_lds<256, 128, 128, 128>(agg1, xb, Wt1, acc, sA, m_base);
#pragma unroll
    for (int nt = 0; nt < 4; nt++) {
        int n = wn * 64 + nt * 16 + l16;
        float bv = loadf(bias, n, f32);
#pragma unroll
        for (int mt = 0; mt < 4; mt++) {
#pragma unroll
            for (int r = 0; r < 4; r++) {
                int m = m_base + wm * 64 + mt * 16 + quad * 4 + r;
                if (m < Nn) {
                    float v = acc[mt][nt][r] + bv;
                    v = v > 0.f ? v : 0.f;
                    Acat[(size_t)m * 512 + 256 + n] = f2bf(v);
                }
            }
        }
    }
}

// layer 2: out = [agg2|h] @ Wt2 + b2 (f32 path in-place over Acat, block-exclusive rows)
__global__ __launch_bounds__(512) void k_gemm2(const unsigned short* __restrict__ Wt2,
                                               const void* __restrict__ bias,
                                               const int* __restrict__ flag,
                                               unsigned short* __restrict__ acat_ws,
                                               void* __restrict__ out) {
    __shared__ unsigned short sA[8192];
    int f32 = flag[1];
    unsigned short* Acat = f32 ? (unsigned short*)out : acat_ws;
    int wid = threadIdx.x >> 6, lane = threadIdx.x & 63;
    int wm = wid & 1, wn = wid >> 1;
    int quad = lane >> 4, l16 = lane & 15;
    int m_base = blockIdx.x * 128;
    floatx4 acc[4][4] = {};
    gemm_core_lds<512, 256, 512, 512>(Acat, Acat + 256, Wt2, acc, sA, m_base);
    __syncthreads();
#pragma unroll
    for (int nt = 0; nt < 4; nt++) {
        int n = wn * 64 + nt * 16 + l16;
        float bv = loadf(bias, n, f32);
#pragma unroll
        for (int mt = 0; mt < 4; mt++) {
#pragma unroll
            for (int r = 0; r < 4; r++) {
                int m = m_base + wm * 64 + mt * 16 + quad * 4 + r;
                if (m < Nn) {
                    float v = acc[mt][nt][r] + bv;
                    if (f32) ((float*)out)[(size_t)m * Hd + n] = v;
                    else     ((unsigned short*)out)[(size_t)m * Hd + n] = f2bf(v);
                }
            }
        }
    }
}

extern "C" void kernel_launch(void* const* d_in, const int* in_sizes, int n_in,
                              void* d_out, int out_size, void* d_ws, size_t ws_size,
                              hipStream_t stream) {
    const void* x   = d_in[0];
    const int*  ei  = (const int*)d_in[1];
    const void* Wl1 = d_in[2];
    const void* Wr1 = d_in[3];
    const void* b1  = d_in[4];
    const void* Wl2 = d_in[5];
    const void* Wr2 = d_in[6];
    const void* b2  = d_in[7];

    char* ws = (char*)d_ws;
    size_t off_cnt    = 0;
    size_t off_cur    = off_cnt + (size_t)Nn * 4;
    size_t off_rowptr = off_cur + (size_t)Nn * 4;
    size_t off_srcl   = off_rowptr + (size_t)(Nn + 4) * 4;
    size_t off_flag   = off_srcl + (size_t)Ee * 4;
    size_t off_bsum   = ((off_flag + 8 + 255) / 256) * 256;   // NB ints
    size_t off_bpre   = off_bsum + 128 * 4;                   // NB ints
    size_t off_wt1    = off_bpre + 128 * 4;
    size_t off_wt2    = off_wt1 + 256 * 256 * 2;
    size_t off_xb     = off_wt2 + 256 * 512 * 2;
    size_t off_agg1   = off_xb + (size_t)Nn * Fin * 2;
    size_t off_acat   = off_agg1 + (size_t)Nn * Fin * 2;  // only touched in bf16 mode

    int*            cnt     = (int*)(ws + off_cnt);
    int*            cur     = (int*)(ws + off_cur);
    int*            rowptr  = (int*)(ws + off_rowptr);
    int*            srcl    = (int*)(ws + off_srcl);
    int*            flag    = (int*)(ws + off_flag);
    int*            bsum    = (int*)(ws + off_bsum);
    int*            bpre    = (int*)(ws + off_bpre);
    unsigned short* Wt1     = (unsigned short*)(ws + off_wt1);
    unsigned short* Wt2     = (unsigned short*)(ws + off_wt2);
    unsigned short* xb      = (unsigned short*)(ws + off_xb);
    unsigned short* agg1    = (unsigned short*)(ws + off_agg1);
    unsigned short* acat_ws = (unsigned short*)(ws + off_acat);

    k_detect<<<1, 64, 0, stream>>>((const unsigned int*)ei, (const unsigned short*)x, flag);
    k_zero<<<(2 * Nn + 255) / 256, 256, 0, stream>>>(cnt, 2 * Nn);
    k_convert<<<(Nn * Fin / 4 + 255) / 256, 256, 0, stream>>>(x, xb, flag);
    k_prep<<<768, 256, 0, stream>>>(Wl1, Wr1, Wl2, Wr2, Wt1, Wt2, flag);

    int eb = (Ee + 255) / 256;
    k_count<<<eb, 256, 0, stream>>>(ei, flag, cnt);
    k_bsum<<<NB, 256, 0, stream>>>(cnt, bsum);
    k_bscan<<<1, 128, 0, stream>>>(bsum, bpre, rowptr);
    k_rowptr<<<NB, 256, 0, stream>>>(cnt, bpre, rowptr);
    k_fill<<<eb, 256, 0, stream>>>(ei, flag, rowptr, cur, srcl);

    int ab = (Nn * 64 + 255) / 256;
    int gx = (Nn + 127) / 128;

    k_agg1<<<ab, 256, 0, stream>>>(xb, agg1, rowptr, srcl);
    k_gemm1<<<gx, 512, 0, stream>>>(agg1, xb, Wt1, b1, flag, acat_ws, d_out);
    k_agg2<<<ab, 256, 0, stream>>>(rowptr, srcl, flag, acat_ws, d_out);
    k_gemm2<<<gx, 512, 0, stream>>>(Wt2, b2, flag, acat_ws, d_out);
}